// Round 1
// 986.507 us; speedup vs baseline: 1.0083x; 1.0083x over previous
//
#include <hip/hip_runtime.h>
#include <math.h>

// ============================================================================
// HypersphereBlock (nGPT-style transformer block), MI355X / gfx950.
// I/O dtype: fp32. Internal compute: bf16 MFMA, fp32 accum.
// B=2 S=2048 D=2048 H=16 hd=128 F=8192.
// R8: gemm_bt (128^2, 2-barrier K-loop, ~534 TF) replaced by gemm256:
//   256x256 tile, BK=64, 8 waves / 512 thr, 128KiB dynamic-LDS double buffer,
//   XOR 16B-slot swizzle (conflict-free ds_read_b128), 4 phases per K-tile
//   (16 MFMA each) with raw s_barrier + s_setprio, counted s_waitcnt vmcnt(4)
//   (never 0 in steady state; B(kt+1) staged at phase 0, A(kt+2) at phase 3).
// Attention / norms / f2b unchanged from R7.
// ws: bf16 W 100.7M | hb f32 33.5M | qb 16.8 | kb 16.8 | vtb 16.8 | xb 16.8
//     | 16.7 tail; mid(67MB) overlays kb..tail. => 218.1 MB.
// ============================================================================

typedef unsigned short ushort_t;
typedef __attribute__((ext_vector_type(8))) short short8;
typedef __attribute__((ext_vector_type(4))) short short4v;
typedef __attribute__((ext_vector_type(4))) float f32x4;

#define S_LEN 2048
#define D_DIM 2048
#define F_DIM 8192
#define NHEAD 16
#define HDIM 128
#define BATCH 2
#define MROWS (BATCH * S_LEN)

__device__ __forceinline__ float bf2f(ushort_t u) {
  union { unsigned int i; float f; } c; c.i = ((unsigned int)u) << 16; return c.f;
}
__device__ __forceinline__ ushort_t f2bf(float f) {
  union { unsigned int i; float f; } c; c.f = f;
  unsigned int u = c.i;
  unsigned int r = (u + 0x7FFFu + ((u >> 16) & 1u)) >> 16;  // RNE
  return (ushort_t)r;
}
__device__ __forceinline__ void load_lds16(const ushort_t* g, ushort_t* l) {
  __builtin_amdgcn_global_load_lds((const __attribute__((address_space(1))) void*)g,
                                   (__attribute__((address_space(3))) void*)l,
                                   16, 0, 0);
}
__device__ __forceinline__ f32x4 mf(short8 a, short8 b, f32x4 c) {
  return __builtin_amdgcn_mfma_f32_16x16x32_bf16(a, b, c, 0, 0, 0);
}

// ---------------------------------------------------------------------------
// merged fp32->bf16 weight conversion. Outputs contiguous in ws:
// [Wq|Wk|Wv|Wo (4xDD)][Win|Wout (2xFD)]. 4 elems/thread.
// ---------------------------------------------------------------------------
__global__ __launch_bounds__(256) void f2b_all_kernel(const float* __restrict__ wq,
                                                      const float* __restrict__ wk,
                                                      const float* __restrict__ wv,
                                                      const float* __restrict__ wo,
                                                      const float* __restrict__ wi,
                                                      const float* __restrict__ wu,
                                                      ushort_t* __restrict__ out) {
  const size_t DD = (size_t)D_DIM * D_DIM;
  const size_t FD = (size_t)F_DIM * D_DIM;
  const size_t e = ((size_t)blockIdx.x * 256 + threadIdx.x) * 4;  // concat elem idx
  const float* src;
  size_t off;
  if (e < 4 * DD) {
    const int wsel = (int)(e >> 22);                  // e / DD
    src = (wsel == 0) ? wq : (wsel == 1) ? wk : (wsel == 2) ? wv : wo;
    off = e & (DD - 1);
  } else if (e < 4 * DD + FD) {
    src = wi; off = e - 4 * DD;
  } else {
    src = wu; off = e - 4 * DD - FD;
  }
  float4 v = *(const float4*)(src + off);
  short4v o;
  o[0] = (short)f2bf(v.x); o[1] = (short)f2bf(v.y);
  o[2] = (short)f2bf(v.z); o[3] = (short)f2bf(v.w);
  *(short4v*)(out + e) = o;
}

// ---------------------------------------------------------------------------
__global__ __launch_bounds__(256) void hsnorm_kernel(const float* __restrict__ x,
                                                     const float* __restrict__ g,
                                                     ushort_t* __restrict__ out) {
  const int row = blockIdx.x;
  const int t = threadIdx.x;
  const size_t base = (size_t)row * D_DIM + t * 8;
  float4 x0 = *(const float4*)(x + base);
  float4 x1 = *(const float4*)(x + base + 4);
  float f[8] = {x0.x, x0.y, x0.z, x0.w, x1.x, x1.y, x1.z, x1.w};
  float ss = 0.f;
#pragma unroll
  for (int j = 0; j < 8; ++j) ss += f[j] * f[j];
#pragma unroll
  for (int o = 32; o >= 1; o >>= 1) ss += __shfl_xor(ss, o);
  __shared__ float red[4];
  if ((t & 63) == 0) red[t >> 6] = ss;
  __syncthreads();
  const float tot = red[0] + red[1] + red[2] + red[3];
  const float factor = 45.254833995939045f / (sqrtf(tot) + 1e-6f);  // sqrt(2048)
  float4 g0 = *(const float4*)(g + t * 8);
  float4 g1 = *(const float4*)(g + t * 8 + 4);
  float gg[8] = {g0.x, g0.y, g0.z, g0.w, g1.x, g1.y, g1.z, g1.w};
  short8 ov;
#pragma unroll
  for (int j = 0; j < 8; ++j) ov[j] = (short)f2bf(f[j] * factor * gg[j]);
  *(short8*)(out + base) = ov;
}

// ---------------------------------------------------------------------------
__global__ __launch_bounds__(256) void qknorm_kernel(ushort_t* __restrict__ buf, float scale) {
  const int wv = threadIdx.x >> 6;
  const int lane = threadIdx.x & 63;
  const size_t vi = (size_t)blockIdx.x * 4 + wv;
  ushort_t* p = buf + vi * 128 + lane * 2;
  const float a = bf2f(p[0]), b = bf2f(p[1]);
  float ss = a * a + b * b;
#pragma unroll
  for (int o = 32; o >= 1; o >>= 1) ss += __shfl_xor(ss, o);
  const float f = scale / (sqrtf(ss) + 1e-6f);
  p[0] = f2bf(a * f);
  p[1] = f2bf(b * f);
}

// ---------------------------------------------------------------------------
// GEMM 256x256 tile: C[M,N] = epi(A[M,K]_bf16 · W[N,K]_bf16^T (+ RES_fp32)).
// 512 threads = 8 waves (2M x 4N); per-wave output 128x64 (8x4 frags).
// BK=64; K-tile = 4 phases (one C-quadrant x K=64, 16 MFMA each), each phase:
//   {ds_reads | stage-issue} -> s_barrier -> setprio(1) MFMA setprio(0)
//   -> [counted vmcnt at phase 3] -> s_barrier.
// LDS 128KiB dynamic: A buf p at p*32768, B at 65536+p*32768.
// Layout: row*128B; 16B slot s stored at s^(row&7)  (conflict-free b128 reads;
// global_load_lds keeps LINEAR dest, the swizzle is applied to the per-lane
// global SOURCE address — both-sides-or-neither rule).
// Staging schedule (provable, counted): prologue A0,B0,A1 + vmcnt(4);
// body kt: ph0 stage B(kt+1)->buf 1-p (its readers finished at kt-1/ph2),
// ph3 stage A(kt+2)->buf p (own readers finished at kt/ph2 barrier);
// boundary: vmcnt(4) leaves exactly A(kt+2) in flight. Tail drains with 0.
// EPI: 1 = +RES fp32, store fp32; 2 = exact GELU, store bf16; 4 = QKV routing.
// Requires M%256==0, N%256==0, K%128==0.
// ---------------------------------------------------------------------------
template <int EPI>
__global__ __launch_bounds__(512, 2) void gemm256(const ushort_t* __restrict__ A,
                                                  const ushort_t* __restrict__ W,
                                                  const float* __restrict__ RES,
                                                  void* __restrict__ Cv,
                                                  int M, int N, int K) {
  extern __shared__ char smem[];
  const int tid = threadIdx.x;
  const int w = tid >> 6;
  const int lane = tid & 63;
  const int quad = lane >> 4;
  const int l15 = lane & 15;
  const int wr = w >> 2, wc = w & 3;
  const long bm = (long)blockIdx.x * 256;
  const long bn = (long)blockIdx.y * 256;

  // LDS read offsets (bytes). row&7 == l15&7 for every fragment row.
  const int sw = l15 & 7;
  const int arow = (wr * 128 + l15) << 7;
  const int a_off0 = arow + ((quad ^ sw) << 4);            // kk=0: slot quad
  const int a_off1 = arow + (((4 | quad) ^ sw) << 4);      // kk=1: slot 4+quad
  const int brow = (wc * 64 + l15) << 7;
  const int b_off0 = 65536 + brow + ((quad ^ sw) << 4);
  const int b_off1 = 65536 + brow + (((4 | quad) ^ sw) << 4);

  // staging: thread covers row sr (+64*ld), source col pre-swizzled so the
  // LINEAR gload_lds dest lands data where the swizzled reads expect it.
  const int sr = tid >> 3;
  const int ss = ((tid & 7) ^ (sr & 7)) << 3;
  const ushort_t* gA = A + (size_t)(bm + sr) * K + ss;
  const ushort_t* gB = W + (size_t)(bn + sr) * K + ss;
  const size_t rstep = (size_t)64 * K;
  const int sdst = w * 1024;  // wave-uniform LDS dest base (+ lane*16 by HW)

#define STAGE_A(PB, GP)                                                        \
  {                                                                            \
    _Pragma("unroll") for (int ld = 0; ld < 4; ++ld)                           \
        load_lds16((GP) + ld * rstep,                                          \
                   (ushort_t*)(smem + (PB)*32768 + ld * 8192 + sdst));         \
  }
#define STAGE_B(PB, GP)                                                        \
  {                                                                            \
    _Pragma("unroll") for (int ld = 0; ld < 4; ++ld)                           \
        load_lds16((GP) + ld * rstep,                                          \
                   (ushort_t*)(smem + 65536 + (PB)*32768 + ld * 8192 + sdst)); \
  }

  f32x4 acc[8][4] = {};
  short8 af[4][2], bf[4][2];
  const int NT = K >> 6;

  // ---- prologue: K0 (A+B) and A(1); counted wait leaves A(1) in flight.
  STAGE_A(0, gA);
  STAGE_B(0, gB);
  STAGE_A(1, gA + 64);
  gA += 128;
  gB += 64;
  asm volatile("s_waitcnt vmcnt(4)" ::: "memory");
  __builtin_amdgcn_s_barrier();

  for (int kt0 = 0; kt0 < NT; kt0 += 2) {
#pragma unroll
    for (int pp = 0; pp < 2; ++pp) {
      const int kt = kt0 + pp;
      const char* sa = smem + pp * 32768;
      // ---------------- phase 0: read a(ih0), b(jh0); stage B(kt+1) --------
#pragma unroll
      for (int i = 0; i < 4; ++i) {
        af[i][0] = *(const short8*)(sa + a_off0 + i * 2048);
        af[i][1] = *(const short8*)(sa + a_off1 + i * 2048);
      }
#pragma unroll
      for (int j = 0; j < 2; ++j) {
        bf[j][0] = *(const short8*)(sa + b_off0 + j * 2048);
        bf[j][1] = *(const short8*)(sa + b_off1 + j * 2048);
      }
      if (kt + 1 < NT) STAGE_B(1 - pp, gB);
      gB += 64;
      __builtin_amdgcn_s_barrier();
      __builtin_amdgcn_s_setprio(1);
#pragma unroll
      for (int i = 0; i < 4; ++i)
#pragma unroll
        for (int j = 0; j < 2; ++j) {
          acc[i][j] = mf(af[i][0], bf[j][0], acc[i][j]);
          acc[i][j] = mf(af[i][1], bf[j][1], acc[i][j]);
        }
      __builtin_amdgcn_s_setprio(0);
      __builtin_amdgcn_s_barrier();
      // ---------------- phase 1: read b(jh1) -------------------------------
#pragma unroll
      for (int j = 0; j < 2; ++j) {
        bf[2 + j][0] = *(const short8*)(sa + b_off0 + (2 + j) * 2048);
        bf[2 + j][1] = *(const short8*)(sa + b_off1 + (2 + j) * 2048);
      }
      __builtin_amdgcn_s_barrier();
      __builtin_amdgcn_s_setprio(1);
#pragma unroll
      for (int i = 0; i < 4; ++i)
#pragma unroll
        for (int j = 0; j < 2; ++j) {
          acc[i][2 + j] = mf(af[i][0], bf[2 + j][0], acc[i][2 + j]);
          acc[i][2 + j] = mf(af[i][1], bf[2 + j][1], acc[i][2 + j]);
        }
      __builtin_amdgcn_s_setprio(0);
      __builtin_amdgcn_s_barrier();
      // ---------------- phase 2: read a(ih1) -------------------------------
#pragma unroll
      for (int i = 0; i < 4; ++i) {
        af[i][0] = *(const short8*)(sa + a_off0 + (4 + i) * 2048);
        af[i][1] = *(const short8*)(sa + a_off1 + (4 + i) * 2048);
      }
      __builtin_amdgcn_s_barrier();
      __builtin_amdgcn_s_setprio(1);
#pragma unroll
      for (int i = 0; i < 4; ++i)
#pragma unroll
        for (int j = 0; j < 2; ++j) {
          acc[4 + i][2 + j] = mf(af[i][0], bf[2 + j][0], acc[4 + i][2 + j]);
          acc[4 + i][2 + j] = mf(af[i][1], bf[2 + j][1], acc[4 + i][2 + j]);
        }
      __builtin_amdgcn_s_setprio(0);
      __builtin_amdgcn_s_barrier();
      // ---------------- phase 3: stage A(kt+2); counted boundary wait ------
      // buf-p A reads finished at phase-2's closing barrier -> write is safe.
      if (kt + 2 < NT) STAGE_A(pp, gA);
      gA += 64;
      __builtin_amdgcn_s_barrier();
      __builtin_amdgcn_s_setprio(1);
#pragma unroll
      for (int i = 0; i < 4; ++i)
#pragma unroll
        for (int j = 0; j < 2; ++j) {
          acc[4 + i][j] = mf(af[i][0], bf[j][0], acc[4 + i][j]);
          acc[4 + i][j] = mf(af[i][1], bf[j][1], acc[4 + i][j]);
        }
      __builtin_amdgcn_s_setprio(0);
      if (kt + 2 < NT) {
        asm volatile("s_waitcnt vmcnt(4)" ::: "memory");  // A(kt+2) stays in flight
      } else {
        asm volatile("s_waitcnt vmcnt(0)" ::: "memory");  // tail drain
      }
      __builtin_amdgcn_s_barrier();
    }
  }
#undef STAGE_A
#undef STAGE_B

  // ---- epilogue ----
  const size_t SZq = (size_t)MROWS * D_DIM;
#pragma unroll
  for (int i = 0; i < 8; ++i) {
    const long row0 = bm + wr * 128 + i * 16 + quad * 4;
#pragma unroll
    for (int j = 0; j < 4; ++j) {
      const long col = bn + wc * 64 + j * 16 + l15;
      if (EPI == 4) {
        if (col < 4096) {  // q or k, row-major stride D_DIM
          ushort_t* dst = (ushort_t*)Cv + (col < 2048 ? 0 : SZq);
          const long c = col & (D_DIM - 1);
#pragma unroll
          for (int r = 0; r < 4; ++r)
            dst[(size_t)(row0 + r) * D_DIM + c] = f2bf(acc[i][j][r]);
        } else {           // v^T per head: vt[((b*16+h)*128+d)*S + s]
          const long b = row0 >> 11;
          const long s0 = row0 & (S_LEN - 1);
          const long h = (col >> 7) & 15;
          const long d = col & (HDIM - 1);
          short4v ov;
#pragma unroll
          for (int r = 0; r < 4; ++r) ov[r] = (short)f2bf(acc[i][j][r]);
          *(short4v*)((ushort_t*)Cv + 2 * SZq + ((b * NHEAD + h) * HDIM + d) * S_LEN + s0) = ov;
        }
      } else {
#pragma unroll
        for (int r = 0; r < 4; ++r) {
          float v = acc[i][j][r];
          const size_t idx = (size_t)(row0 + r) * N + col;
          if (EPI == 1) {
            ((float*)Cv)[idx] = v + RES[idx];
          } else if (EPI == 2) {
            v = 0.5f * v * (1.0f + erff(v * 0.70710678118654752f));
            ((ushort_t*)Cv)[idx] = f2bf(v);
          }
        }
      }
    }
  }
}

// ---------------------------------------------------------------------------
// Causal flash attention. 4 waves/block, 64-row Q tile (16 rows/wave),
// 64-key K-tiles shared across waves, staged via global_load_lds (w=16).
// qt dispatch REVERSED so heavy diagonal blocks launch first.
// ---------------------------------------------------------------------------
__global__ __launch_bounds__(256) void attn_kernel(const ushort_t* __restrict__ q,
                                                   const ushort_t* __restrict__ k,
                                                   const ushort_t* __restrict__ vt,
                                                   ushort_t* __restrict__ out) {
  __shared__ __align__(16) ushort_t K_lds[64 * 128];
  __shared__ __align__(16) ushort_t Vt_lds[128 * 64];
  __shared__ __align__(16) ushort_t P_lds[4 * 16 * 64];
  const int tid = threadIdx.x;
  const int w = tid >> 6;
  const int lane = tid & 63;
  const int quad = lane >> 4;
  const int l15 = lane & 15;

  const int qt = (S_LEN / 64 - 1) - (blockIdx.x & (S_LEN / 64 - 1));  // reversed
  const int bh = blockIdx.x >> 5;
  const int b = bh >> 4;
  const int h = bh & 15;
  const int q0 = qt * 64;
  const int wrow0 = q0 + w * 16;
  const size_t base = ((size_t)b * S_LEN) * D_DIM + h * HDIM;
  const size_t vtbase = ((size_t)(b * NHEAD + h)) * HDIM * S_LEN;

  short8 qa[4];
#pragma unroll
  for (int st = 0; st < 4; ++st)
    qa[st] = *(const short8*)(q + base + (size_t)(wrow0 + l15) * D_DIM + st * 32 + quad * 8);

  const int kc0 = w * 64 + lane;
  ushort_t* Pw = P_lds + w * 1024;

  f32x4 o[8] = {};
  float m[4], l[4];
#pragma unroll
  for (int r = 0; r < 4; ++r) { m[r] = -__builtin_inff(); l[r] = 0.f; }

  const int ktmax = (q0 + 63) >> 6;
  for (int kt = 0; kt <= ktmax; ++kt) {
#pragma unroll
    for (int r2 = 0; r2 < 4; ++r2) {
      const int c = r2 * 256 + kc0;
      {
        const int db = c >> 8, key = (c >> 2) & 63, dl = (c & 3) * 8;
        load_lds16(k + base + (size_t)(kt * 64 + key) * D_DIM + db * 32 + dl,
                   K_lds + (size_t)(r2 * 4 + w) * 512);
      }
      {
        const int kc = c >> 9, d = (c >> 2) & 127, kl = (c & 3) * 8;
        load_lds16(vt + vtbase + (size_t)d * S_LEN + kt * 64 + kc * 32 + kl,
                   Vt_lds + (size_t)(r2 * 4 + w) * 512);
      }
    }
    __syncthreads();

    if (kt * 64 <= wrow0 + 15) {
      f32x4 s[4];
#pragma unroll
      for (int h2 = 0; h2 < 4; ++h2) {
        f32x4 sa = {};
#pragma unroll
        for (int st = 0; st < 4; ++st) {
          short8 kb = *(const short8*)&K_lds[st * 2048 + (h2 * 16 + l15) * 32 + quad * 8];
          sa = __builtin_amdgcn_mfma_f32_16x16x32_bf16(qa[st], kb, sa, 0, 0, 0);
        }
        s[h2] = sa;
      }

      const int kbase = kt * 64 + l15;
      float alpha[4];
#pragma unroll
      for (int r = 0; r < 4; ++r) {
        const int qrow = wrow0 + quad * 4 + r;
        float sv[4];
#pragma unroll
        for (int h2 = 0; h2 < 4; ++h2)
          sv[h2] = (kbase + h2 * 16 <= qrow) ? s[h2][r] : -__builtin_inff();
        float tmax = fmaxf(fmaxf(sv[0], sv[1]), fmaxf(sv[2], sv[3]));
#pragma unroll
        for (int off = 8; off >= 1; off >>= 1) tmax = fmaxf(tmax, __shfl_xor(tmax, off));
        const float mn = fmaxf(m[r], tmax);
        const float al = __expf(m[r] - mn);
        float p[4], ps = 0.f;
#pragma unroll
        for (int h2 = 0; h2 < 4; ++h2) { p[h2] = __expf(sv[h2] - mn); ps += p[h2]; }
#pragma unroll
        for (int off = 8; off >= 1; off >>= 1) ps += __shfl_xor(ps, off);
        l[r] = l[r] * al + ps;
        m[r] = mn;
        alpha[r] = al;
#pragma unroll
        for (int h2 = 0; h2 < 4; ++h2)
          Pw[(h2 >> 1) * 512 + (quad * 4 + r) * 32 + (h2 & 1) * 16 + l15] = f2bf(p[h2]);
      }

#pragma unroll
      for (int c = 0; c < 8; ++c)
#pragma unroll
        for (int r = 0; r < 4; ++r) o[c][r] *= alpha[r];

      short8 af0 = *(const short8*)&Pw[l15 * 32 + quad * 8];
      short8 af1 = *(const short8*)&Pw[512 + l15 * 32 + quad * 8];
#pragma unroll
      for (int c = 0; c < 8; ++c) {
        short8 vb0 = *(const short8*)&Vt_lds[(c * 16 + l15) * 32 + quad * 8];
        o[c] = __builtin_amdgcn_mfma_f32_16x16x32_bf16(af0, vb0, o[c], 0, 0, 0);
        short8 vb1 = *(const short8*)&Vt_lds[4096 + (c * 16 + l15) * 32 + quad * 8];
        o[c] = __builtin_amdgcn_mfma_f32_16x16x32_bf16(af1, vb1, o[c], 0, 0, 0);
      }
    }
    __syncthreads();
  }

#pragma unroll
  for (int c = 0; c < 8; ++c)
#pragma unroll
    for (int r = 0; r < 4; ++r) {
      const float val = o[c][r] / l[r];
      out[base + (size_t)(wrow0 + quad * 4 + r) * D_DIM + c * 16 + l15] = f2bf(val);
    }
}

// ---------------------------------------------------------------------------
extern "C" void kernel_launch(void* const* d_in, const int* in_sizes, int n_in,
                              void* d_out, int out_size, void* d_ws, size_t ws_size,
                              hipStream_t stream) {
  const float* hid  = (const float*)d_in[0];
  const float* Wq   = (const float*)d_in[1];
  const float* Wk   = (const float*)d_in[2];
  const float* Wv   = (const float*)d_in[3];
  const float* Wo   = (const float*)d_in[4];
  const float* Win  = (const float*)d_in[5];
  const float* Wout = (const float*)d_in[6];
  // d_in[7] = qk_norm_factor == 1/sqrt(128), folded in as exact constant.
  const float* ga   = (const float*)d_in[8];
  const float* gm   = (const float*)d_in[9];
  float* out = (float*)d_out;

  const size_t DD = (size_t)D_DIM * D_DIM;
  const size_t FD = (size_t)F_DIM * D_DIM;
  const size_t SZ = (size_t)MROWS * D_DIM;

  ushort_t* wqb  = (ushort_t*)d_ws;     // wq|wk|wv contiguous = stacked [6144,2048]
  ushort_t* wob  = wqb + 3 * DD;
  ushort_t* winb = wob + DD;
  ushort_t* woutb= winb + FD;
  float*    hb   = (float*)(woutb + FD);      // h (fp32)
  ushort_t* qb   = (ushort_t*)(hb + SZ);      // q, later y_norm
  ushort_t* kb   = qb + SZ;                   // k      (qb+SZ: EPI4 contract)
  ushort_t* vtb  = kb + SZ;                   // v^T per head (qb+2SZ)
  ushort_t* xb   = vtb + SZ;                  // x_norm, later attn-out
  ushort_t* mid  = kb;                        // 67MB, overlays kb|vtb|xb + tail

  // one-time opt-in for 128 KiB dynamic LDS (capture-safe: no stream op)
  static int attr_set = 0;
  if (!attr_set) {
    hipFuncSetAttribute((const void*)&gemm256<1>,
                        hipFuncAttributeMaxDynamicSharedMemorySize, 131072);
    hipFuncSetAttribute((const void*)&gemm256<2>,
                        hipFuncAttributeMaxDynamicSharedMemorySize, 131072);
    hipFuncSetAttribute((const void*)&gemm256<4>,
                        hipFuncAttributeMaxDynamicSharedMemorySize, 131072);
    attr_set = 1;
  }

  // one merged weight conversion (outputs contiguous at wqb)
  f2b_all_kernel<<<(unsigned)((4 * DD + 2 * FD) / 1024), 256, 0, stream>>>(
      Wq, Wk, Wv, Wo, Win, Wout, wqb);

  hsnorm_kernel<<<MROWS, 256, 0, stream>>>(hid, ga, xb);
  // fused QKV: A=xb, W=[Wq;Wk;Wv] stacked, routed epilogue
  gemm256<4><<<dim3(MROWS / 256, 6144 / 256), 512, 131072, stream>>>(
      xb, wqb, nullptr, qb, MROWS, 6144, D_DIM);
  qknorm_kernel<<<(MROWS * NHEAD) / 4, 256, 0, stream>>>(qb, 0.08838834764831845f);
  qknorm_kernel<<<(MROWS * NHEAD) / 4, 256, 0, stream>>>(kb, 1.0f);
  attn_kernel<<<BATCH * NHEAD * (S_LEN / 64), 256, 0, stream>>>(qb, kb, vtb, xb);
  gemm256<1><<<dim3(MROWS / 256, D_DIM / 256), 512, 131072, stream>>>(
      xb, wob, hid, hb, MROWS, D_DIM, D_DIM);
  hsnorm_kernel<<<MROWS, 256, 0, stream>>>(hb, gm, qb);
  gemm256<2><<<dim3(MROWS / 256, F_DIM / 256), 512, 131072, stream>>>(
      qb, winb, nullptr, mid, MROWS, F_DIM, D_DIM);
  gemm256<1><<<dim3(MROWS / 256, D_DIM / 256), 512, 131072, stream>>>(
      mid, woutb, hb, out, MROWS, D_DIM, F_DIM);
}